// Round 7
// baseline (2166.250 us; speedup 1.0000x reference)
//
#include <hip/hip_runtime.h>

typedef float f32x4 __attribute__((ext_vector_type(4)));
typedef __bf16 bf16x8 __attribute__((ext_vector_type(8)));
typedef unsigned int u32x4 __attribute__((ext_vector_type(4)));

#define DI __device__ __forceinline__

constexpr int B_ = 4, T_ = 2048, C_ = 2048, H_ = 32;
constexpr int M_ = B_ * T_;  // 8192 rows

DI unsigned short f2bf(float f) {
  unsigned u = __float_as_uint(f);
  return (unsigned short)((u + 0x7FFFu + ((u >> 16) & 1u)) >> 16);
}
DI float bf2f(unsigned short h) { return __uint_as_float(((unsigned)h) << 16); }

DI void gl16(const void* g, void* l) {
  __builtin_amdgcn_global_load_lds(
      (__attribute__((address_space(1))) const unsigned int*)g,
      (__attribute__((address_space(3))) unsigned int*)l, 16, 0, 0);
}

// 8-lane sum, pure DPP: quad_perm(xor1), quad_perm(xor2), row_half_mirror.
// All 8 lanes of each aligned 8-lane group end with the group total.
DI float rsum8(float x) {
  int t = __builtin_amdgcn_update_dpp(0, __float_as_int(x), 0xB1, 0xF, 0xF, true);
  x += __int_as_float(t);
  t = __builtin_amdgcn_update_dpp(0, __float_as_int(x), 0x4E, 0xF, 0xF, true);
  x += __int_as_float(t);
  t = __builtin_amdgcn_update_dpp(0, __float_as_int(x), 0x141, 0xF, 0xF, true);
  x += __int_as_float(t);
  return x;
}

// ---------------- transpose f32 (R x C) -> bf16 (C x R) ----------------
__global__ __launch_bounds__(256) void k_transpose(const float* __restrict__ in,
                                                   unsigned short* __restrict__ out,
                                                   int R, int C) {
  __shared__ float tile[32][33];
  int c0 = blockIdx.x * 32, r0 = blockIdx.y * 32;
  int tx = threadIdx.x & 31, ty = threadIdx.x >> 5;
#pragma unroll
  for (int i = 0; i < 4; ++i) {
    int r = r0 + ty * 4 + i, c = c0 + tx;
    if (r < R && c < C) tile[ty * 4 + i][tx] = in[(size_t)r * C + c];
  }
  __syncthreads();
#pragma unroll
  for (int i = 0; i < 4; ++i) {
    int c = c0 + ty * 4 + i, r = r0 + tx;
    if (r < R && c < C) out[(size_t)c * R + r] = f2bf(tile[tx][ty * 4 + i]);
  }
}

// ---------------- token-shift mix prep: 3 coef sets, x read once ----------------
DI void mix_emit(const float* coef, int c0, size_t off,
                 const float* xv, const float* dx, unsigned short* dst) {
  unsigned short u[8];
#pragma unroll
  for (int i = 0; i < 2; ++i) {
    f32x4 cf = *(const f32x4*)(coef + c0 + i * 4);
#pragma unroll
    for (int j = 0; j < 4; ++j) u[i * 4 + j] = f2bf(xv[i * 4 + j] + dx[i * 4 + j] * cf[j]);
  }
  u32x4 pv;
#pragma unroll
  for (int j = 0; j < 4; ++j) pv[j] = (unsigned)u[2 * j] | ((unsigned)u[2 * j + 1] << 16);
  *(u32x4*)(dst + off) = pv;
}

__global__ __launch_bounds__(256) void k_prep3(
    const float* __restrict__ x, const float* __restrict__ xprev,
    const float* __restrict__ cR, const float* __restrict__ cV,
    const float* __restrict__ cK,
    unsigned short* __restrict__ XR, unsigned short* __restrict__ XV,
    unsigned short* __restrict__ XK) {
  int bt = blockIdx.x;
  int t = bt & (T_ - 1);
  int c0 = threadIdx.x * 8;
  size_t off = (size_t)bt * C_ + c0;
  const float* xp = x + off;
  const float* pp = t ? (xp - C_) : (xprev + (size_t)(bt >> 11) * C_ + c0);
  float xv[8], dx[8];
#pragma unroll
  for (int i = 0; i < 2; ++i) {
    f32x4 a = *(const f32x4*)(xp + i * 4);
    f32x4 p = *(const f32x4*)(pp + i * 4);
#pragma unroll
    for (int j = 0; j < 4; ++j) { xv[i * 4 + j] = a[j]; dx[i * 4 + j] = p[j] - a[j]; }
  }
  mix_emit(cR, c0, off, xv, dx, XR);
  mix_emit(cV, c0, off, xv, dx, XV);
  mix_emit(cK, c0, off, xv, dx, XK);
}

// fused token-shift mix staging (for small down-GEMMs only)
DI void stage_mix(const float* __restrict__ x, const float* __restrict__ xprev,
                  const float* __restrict__ coef, unsigned short* As,
                  int m0, int kt, int wv, int lane) {
  const int lr = lane >> 3, lc = (lane & 7) * 8;
  f32x4 c0 = *(const f32x4*)(coef + kt + lc);
  f32x4 c1 = *(const f32x4*)(coef + kt + lc + 4);
#pragma unroll
  for (int i = 0; i < 4; ++i) {
    int chunk = wv * 4 + i;
    int r = chunk * 8 + lr;
    int m = m0 + r;
    const float* xp = x + (size_t)m * C_ + kt + lc;
    const float* pp = (m & (T_ - 1)) ? (xp - C_)
                                     : (xprev + (size_t)(m >> 11) * C_ + kt + lc);
    f32x4 xv0 = *(const f32x4*)xp, xv1 = *(const f32x4*)(xp + 4);
    f32x4 pv0 = *(const f32x4*)pp, pv1 = *(const f32x4*)(pp + 4);
    unsigned short u[8];
#pragma unroll
    for (int j = 0; j < 4; ++j) u[j] = f2bf(xv0[j] + (pv0[j] - xv0[j]) * c0[j]);
#pragma unroll
    for (int j = 0; j < 4; ++j) u[4 + j] = f2bf(xv1[j] + (pv1[j] - xv1[j]) * c1[j]);
    u32x4 pk;
#pragma unroll
    for (int j = 0; j < 4; ++j) pk[j] = (unsigned)u[2 * j] | ((unsigned)u[2 * j + 1] << 16);
    *(u32x4*)((char*)As + chunk * 1024 + lane * 16) = pk;
  }
}

// ---------------- big GEMM: 128x128 tile, K=2048, XCD-swizzled 1D grid ----------
// grid = 1024: xcd = bid&7 owns m-tiles [xcd*8, xcd*8+8) -> A-panel L2-resident.
// EPI 0: RB = bf16(acc)
// EPI 1: VB = bf16(acc + (vfirst - acc)*svb)
// EPI 2: kk-norm fused: KB, AHB, BHB
// EPI 3: f32 store (final output GEMM)
template <int EPI>
__global__ __launch_bounds__(256, 2) void k_gemm_big(
    const unsigned short* __restrict__ A,
    const unsigned short* __restrict__ Bt,
    float* __restrict__ outF, unsigned short* __restrict__ outB,
    const unsigned short* __restrict__ svb, const float* __restrict__ vfirst,
    const unsigned short* __restrict__ abf,
    const float* __restrict__ k_k, const float* __restrict__ k_a,
    unsigned short* __restrict__ ahb, unsigned short* __restrict__ bhb) {
  __shared__ __align__(16) unsigned short As[128][64];
  __shared__ __align__(16) unsigned short Bs[128][64];
  const int tid = threadIdx.x, lane = tid & 63, wv = tid >> 6;
  const int bid = blockIdx.x;
  const int loc = bid >> 3;
  const int by = (bid & 7) * 8 + (loc & 7);
  const int bx = loc >> 3;
  const int m0 = by * 128, n0 = bx * 128;
  const int wm = (wv >> 1) * 64, wn = (wv & 1) * 64;
  const int lr = lane >> 3, lc = (lane & 7) * 8;
  f32x4 acc[4][4] = {};
  for (int kt = 0; kt < C_; kt += 64) {
    __syncthreads();
#pragma unroll
    for (int i = 0; i < 4; ++i) {
      int chunk = wv * 4 + i, r = chunk * 8 + lr;
      gl16(A + (size_t)(m0 + r) * C_ + kt + lc, (char*)&As[0][0] + chunk * 1024);
      gl16(Bt + (size_t)(n0 + r) * C_ + kt + lc, (char*)&Bs[0][0] + chunk * 1024);
    }
    __syncthreads();
    const int rr = lane & 15;
#pragma unroll
    for (int kh = 0; kh < 2; ++kh) {
      const int kof = kh * 32 + (lane >> 4) * 8;
      bf16x8 af[4], bfv[4];
#pragma unroll
      for (int i = 0; i < 4; ++i) af[i] = *(const bf16x8*)&As[wm + i * 16 + rr][kof];
#pragma unroll
      for (int j = 0; j < 4; ++j) bfv[j] = *(const bf16x8*)&Bs[wn + j * 16 + rr][kof];
#pragma unroll
      for (int i = 0; i < 4; ++i)
#pragma unroll
        for (int j = 0; j < 4; ++j)
          acc[i][j] = __builtin_amdgcn_mfma_f32_16x16x32_bf16(af[i], bfv[j], acc[i][j], 0, 0, 0);
    }
  }
  const int cr = (lane >> 4) * 4, cc2 = lane & 15;
  if constexpr (EPI == 2) {
    float kkv[4], kav[4];
#pragma unroll
    for (int j = 0; j < 4; ++j) {
      int col = n0 + wn + j * 16 + cc2;
      kkv[j] = k_k[col];
      kav[j] = k_a[col];
    }
#pragma unroll
    for (int i = 0; i < 4; ++i)
#pragma unroll
      for (int q = 0; q < 4; ++q) {
        int row = m0 + wm + i * 16 + cr + q;
        float kk4[4], p = 0.f;
#pragma unroll
        for (int j = 0; j < 4; ++j) {
          float kkc = acc[i][j][q] * kkv[j];
          kk4[j] = kkc;
          p += kkc * kkc;
        }
        p += __shfl_xor(p, 1); p += __shfl_xor(p, 2);
        p += __shfl_xor(p, 4); p += __shfl_xor(p, 8);
        float inv = 1.f / fmaxf(sqrtf(p), 1e-12f);
#pragma unroll
        for (int j = 0; j < 4; ++j) {
          int col = n0 + wn + j * 16 + cc2;
          size_t off = (size_t)row * C_ + col;
          float kkn = kk4[j] * inv;
          float a = bf2f(abf[off]);
          ahb[off] = f2bf(-kkn);
          bhb[off] = f2bf(kkn * a);
          outB[off] = f2bf(acc[i][j][q] * (1.f + (a - 1.f) * kav[j]));
        }
      }
  } else {
#pragma unroll
    for (int i = 0; i < 4; ++i)
#pragma unroll
      for (int j = 0; j < 4; ++j)
#pragma unroll
        for (int q = 0; q < 4; ++q) {
          int row = m0 + wm + i * 16 + cr + q;
          int col = n0 + wn + j * 16 + cc2;
          size_t off = (size_t)row * C_ + col;
          float v = acc[i][j][q];
          if constexpr (EPI == 0) {
            outB[off] = f2bf(v);
          } else if constexpr (EPI == 1) {
            float s = bf2f(svb[off]);
            outB[off] = f2bf(v + (vfirst[off] - v) * s);
          } else {
            outF[off] = v;
          }
        }
  }
}

// ---------------- down GEMM body (shared by the merged k_down4) ----------------
template <int N, int ACT, bool FUSED>
DI void down_body(int m0, unsigned short (*As)[64], unsigned short (*Bs)[64],
                  const unsigned short* __restrict__ A,
                  const float* __restrict__ x, const float* __restrict__ xprev,
                  const float* __restrict__ coef, const unsigned short* __restrict__ Bt,
                  unsigned short* __restrict__ out) {
  const int tid = threadIdx.x, lane = tid & 63, wv = tid >> 6;
  const int wm = wv * 32;
  const int lr = lane >> 3, lc = (lane & 7) * 8;
  f32x4 acc[2][N / 16] = {};
  for (int kt = 0; kt < C_; kt += 64) {
    __syncthreads();
    if constexpr (FUSED) {
      stage_mix(x, xprev, coef, &As[0][0], m0, kt, wv, lane);
    } else {
#pragma unroll
      for (int i = 0; i < 4; ++i) {
        int chunk = wv * 4 + i, r = chunk * 8 + lr;
        gl16(A + (size_t)(m0 + r) * C_ + kt + lc, (char*)&As[0][0] + chunk * 1024);
      }
    }
#pragma unroll
    for (int i = 0; i < N / 32; ++i) {
      int chunk = wv * (N / 32) + i, r = chunk * 8 + lr;
      gl16(Bt + (size_t)r * C_ + kt + lc, (char*)&Bs[0][0] + chunk * 1024);
    }
    __syncthreads();
    const int rr = lane & 15;
#pragma unroll
    for (int kh = 0; kh < 2; ++kh) {
      const int kof = kh * 32 + (lane >> 4) * 8;
      bf16x8 af[2], bfv[N / 16];
#pragma unroll
      for (int i = 0; i < 2; ++i) af[i] = *(const bf16x8*)&As[wm + i * 16 + rr][kof];
#pragma unroll
      for (int j = 0; j < N / 16; ++j) bfv[j] = *(const bf16x8*)&Bs[j * 16 + rr][kof];
#pragma unroll
      for (int i = 0; i < 2; ++i)
#pragma unroll
        for (int j = 0; j < N / 16; ++j)
          acc[i][j] = __builtin_amdgcn_mfma_f32_16x16x32_bf16(af[i], bfv[j], acc[i][j], 0, 0, 0);
    }
  }
  const int cr = (lane >> 4) * 4, cc2 = lane & 15;
#pragma unroll
  for (int i = 0; i < 2; ++i)
#pragma unroll
    for (int j = 0; j < N / 16; ++j)
#pragma unroll
      for (int q = 0; q < 4; ++q) {
        int row = m0 + wm + i * 16 + cr + q;
        int col = j * 16 + cc2;
        float v = acc[i][j][q];
        if (ACT == 1) v = tanhf(v);
        else if (ACT == 2) v = 1.f / (1.f + expf(-v));
        out[(size_t)row * N + col] = f2bf(v);
      }
}

// merged down-GEMMs: 256 blocks (4 groups x 64 m-tiles)
__global__ __launch_bounds__(256, 2) void k_down4(
    const float* __restrict__ x, const float* __restrict__ xprev,
    const unsigned short* __restrict__ XMv,
    const float* __restrict__ xw, const float* __restrict__ xa,
    const float* __restrict__ xg,
    const unsigned short* __restrict__ W1T, const unsigned short* __restrict__ A1T,
    const unsigned short* __restrict__ V1T, const unsigned short* __restrict__ G1T,
    unsigned short* __restrict__ HWB, unsigned short* __restrict__ HAB,
    unsigned short* __restrict__ HVB, unsigned short* __restrict__ HGB) {
  __shared__ __align__(16) unsigned short As[128][64];
  __shared__ __align__(16) unsigned short Bs[128][64];
  int g = blockIdx.x >> 6;
  int m0 = (blockIdx.x & 63) * 128;
  if (g == 0)      down_body<64, 1, true>(m0, As, Bs, nullptr, x, xprev, xw, W1T, HWB);
  else if (g == 1) down_body<64, 0, true>(m0, As, Bs, nullptr, x, xprev, xa, A1T, HAB);
  else if (g == 2) down_body<32, 0, false>(m0, As, Bs, XMv, nullptr, nullptr, nullptr, V1T, HVB);
  else             down_body<128, 2, true>(m0, As, Bs, nullptr, x, xprev, xg, G1T, HGB);
}

// ---------------- up GEMM (K in {32,64,128}), single K pass ----------------
// MODE 0: wd = exp(-exp(-softplus(-(bias+up)) - 0.5)) -> outF (f32)
// MODE 1: sigmoid(bias+up) -> outB (bf16)
// MODE 3: up -> outB (bf16)
template <int K, int MODE>
__global__ __launch_bounds__(256, 2) void k_up(
    const unsigned short* __restrict__ A, const unsigned short* __restrict__ Bt,
    const float* __restrict__ bias, float* __restrict__ outF,
    unsigned short* __restrict__ outB) {
  __shared__ __align__(16) unsigned short As[128][K];
  __shared__ __align__(16) unsigned short Bs[128][K];
  const int tid = threadIdx.x, lane = tid & 63, wv = tid >> 6;
  const int m0 = blockIdx.y * 128, n0 = blockIdx.x * 128;
  const int wm = (wv >> 1) * 64, wn = (wv & 1) * 64;
  constexpr int LPR = K / 8;
  constexpr int RPC = 64 / LPR;
  const int lr = lane / LPR, lc = (lane % LPR) * 8;
  f32x4 acc[4][4] = {};
#pragma unroll
  for (int i = 0; i < K / 16; ++i) {
    int chunk = wv * (K / 16) + i;
    int r = chunk * RPC + lr;
    gl16(A + (size_t)(m0 + r) * K + lc, (char*)&As[0][0] + chunk * 1024);
    gl16(Bt + (size_t)(n0 + r) * K + lc, (char*)&Bs[0][0] + chunk * 1024);
  }
  __syncthreads();
  const int rr = lane & 15;
#pragma unroll
  for (int ks = 0; ks < K / 32; ++ks) {
    const int kof = ks * 32 + (lane >> 4) * 8;
    bf16x8 af[4], bfv[4];
#pragma unroll
    for (int i = 0; i < 4; ++i) af[i] = *(const bf16x8*)&As[wm + i * 16 + rr][kof];
#pragma unroll
    for (int j = 0; j < 4; ++j) bfv[j] = *(const bf16x8*)&Bs[wn + j * 16 + rr][kof];
#pragma unroll
    for (int i = 0; i < 4; ++i)
#pragma unroll
      for (int j = 0; j < 4; ++j)
        acc[i][j] = __builtin_amdgcn_mfma_f32_16x16x32_bf16(af[i], bfv[j], acc[i][j], 0, 0, 0);
  }
  const int cr = (lane >> 4) * 4, cc2 = lane & 15;
#pragma unroll
  for (int i = 0; i < 4; ++i)
#pragma unroll
    for (int j = 0; j < 4; ++j)
#pragma unroll
      for (int q = 0; q < 4; ++q) {
        int row = m0 + wm + i * 16 + cr + q;
        int col = n0 + wn + j * 16 + cc2;
        size_t off = (size_t)row * C_ + col;
        float up = acc[i][j][q];
        if (MODE == 0) {
          float z = -(bias[col] + up);
          float sp = fmaxf(z, 0.f) + log1pf(expf(-fabsf(z)));
          outF[off] = expf(-expf(-sp - 0.5f));
        } else if (MODE == 1) {
          outB[off] = f2bf(1.f / (1.f + expf(-(bias[col] + up))));
        } else {
          outB[off] = f2bf(up);
        }
      }
}

// ---------------- WKV recurrent scan: plain-HIP register pipeline ----------------
// 1024 one-wave blocks (R3-proven structure). Block p: wq = p>>7 (row-octet),
// bh = p&127. Lane: rl = lane>>3 (row), e = lane&7 (channel octet). 8 f32/lane.
// 4 named slots, depth-3 prefetch (compiler-managed waits), pure-DPP rsum8,
// batched transposed stores: lane e keeps step t0+e's output, one coalesced
// store per 8 steps into out_tr[bh][row][t] (f32, lives in d_out).
__global__ __launch_bounds__(64) void k_scan(
    const unsigned short* __restrict__ RB, const float* __restrict__ WD,
    const unsigned short* __restrict__ KB, const unsigned short* __restrict__ VB,
    const unsigned short* __restrict__ AHB, const unsigned short* __restrict__ BHB,
    const float* __restrict__ s0, float* __restrict__ out_tr) {
  const int lane = threadIdx.x & 63;
  const int p = blockIdx.x;
  const int wq = p >> 7, bh = p & 127;
  const int b = bh >> 5, h = bh & 31;
  const int e = lane & 7, rl = lane >> 3;
  const int row = wq * 8 + rl;
  const int e8 = e * 8;
  const size_t base = (size_t)b * T_ * C_ + h * 64;
  float S[8];
  {
    const float* sp = s0 + ((size_t)(b * H_ + h) * 64 + row) * 64 + e8;
    f32x4 sA = *(const f32x4*)sp, sB = *(const f32x4*)(sp + 4);
#pragma unroll
    for (int j = 0; j < 4; ++j) { S[j] = sA[j]; S[4 + j] = sB[j]; }
  }
  float* pst = out_tr + ((size_t)bh * 64 + row) * 2048 + e;
  float o_keep = 0.f;

#define DECL_SLOT(n) bf16x8 r##n, k##n, a##n, bb##n; f32x4 wA##n, wB##n; unsigned short v##n;
  DECL_SLOT(0) DECL_SLOT(1) DECL_SLOT(2) DECL_SLOT(3)

#define ISSUE(n, t)                                              \
  {                                                              \
    int ti = (t) < T_ ? (t) : T_ - 1;                            \
    size_t eo = base + (size_t)ti * C_;                          \
    size_t ee = eo + e8;                                         \
    r##n = *(const bf16x8*)(RB + ee);                            \
    k##n = *(const bf16x8*)(KB + ee);                            \
    a##n = *(const bf16x8*)(AHB + ee);                           \
    bb##n = *(const bf16x8*)(BHB + ee);                          \
    wA##n = *(const f32x4*)(WD + ee);                            \
    wB##n = *(const f32x4*)(WD + ee + 4);                        \
    v##n = VB[eo + row];                                         \
  }

#define STEP(n, PH)                                              \
  {                                                              \
    float rr[8], kk[8], aa[8], bv[8], ww[8];                     \
    _Pragma("unroll") for (int j = 0; j < 8; ++j) {              \
      rr[j] = (float)r##n[j];                                    \
      kk[j] = (float)k##n[j];                                    \
      aa[j] = (float)a##n[j];                                    \
      bv[j] = (float)bb##n[j];                                   \
    }                                                            \
    _Pragma("unroll") for (int j = 0; j < 4; ++j) {              \
      ww[j] = wA##n[j];                                          \
      ww[4 + j] = wB##n[j];                                      \
    }                                                            \
    float sa0 = S[0] * aa[0], sa1 = S[1] * aa[1];                \
    _Pragma("unroll") for (int j = 2; j < 8; j += 2) {           \
      sa0 = fmaf(S[j], aa[j], sa0);                              \
      sa1 = fmaf(S[j + 1], aa[j + 1], sa1);                      \
    }                                                            \
    float sa = rsum8(sa0 + sa1);                                 \
    float vi = bf2f(v##n);                                       \
    float o0 = 0.f, o1 = 0.f;                                    \
    _Pragma("unroll") for (int j = 0; j < 8; j += 2) {           \
      S[j] = fmaf(S[j], ww[j], fmaf(sa, bv[j], vi * kk[j]));     \
      S[j + 1] = fmaf(S[j + 1], ww[j + 1],                       \
                      fmaf(sa, bv[j + 1], vi * kk[j + 1]));      \
      o0 = fmaf(S[j], rr[j], o0);                                \
      o1 = fmaf(S[j + 1], rr[j + 1], o1);                        \
    }                                                            \
    float o = rsum8(o0 + o1);                                    \
    o_keep = (e == (PH)) ? o : o_keep;                           \
    if ((PH) == 7) { *pst = o_keep; pst += 8; }                  \
  }

  ISSUE(0, 0) ISSUE(1, 1) ISSUE(2, 2)
#pragma unroll 1
  for (int t = 0; t < T_; t += 8) {
    ISSUE(3, t + 3)  STEP(0, 0)
    ISSUE(0, t + 4)  STEP(1, 1)
    ISSUE(1, t + 5)  STEP(2, 2)
    ISSUE(2, t + 6)  STEP(3, 3)
    ISSUE(3, t + 7)  STEP(0, 4)
    ISSUE(0, t + 8)  STEP(1, 5)
    ISSUE(1, t + 9)  STEP(2, 6)
    ISSUE(2, t + 10) STEP(3, 7)
  }
#undef DECL_SLOT
#undef ISSUE
#undef STEP
}

// ---------------- GroupNorm + bonus + gate, reading transposed scan output -----
// grid 4096: block = one (bh, 64-t tile). LDS-transpose out_tr -> per-t rows.
__global__ __launch_bounds__(256) void k_gn_t(
    const float* __restrict__ out_tr, const unsigned short* __restrict__ rb,
    const unsigned short* __restrict__ kb, const unsigned short* __restrict__ vb,
    const unsigned short* __restrict__ g, const float* __restrict__ r_k,
    const float* __restrict__ lnw, const float* __restrict__ lnb,
    unsigned short* __restrict__ outg) {
  __shared__ float tile[64][65];
  const int bid = blockIdx.x;
  const int bh = bid >> 5, ti = bid & 31;
  const int b = bh >> 5, h = bh & 31;
  const int t0 = ti * 64;
  const int tid = threadIdx.x, lane = tid & 63, wv = tid >> 6;
#pragma unroll
  for (int i = 0; i < 16; ++i) {
    int row = wv * 16 + i;
    tile[lane][row] = out_tr[((size_t)bh * 64 + row) * 2048 + t0 + lane];
  }
  __syncthreads();
  const int c = h * 64 + lane;
  const float rk = r_k[c], lw = lnw[c], lb = lnb[c];
#pragma unroll 1
  for (int j = 0; j < 16; ++j) {
    int tt = wv * 16 + j;
    int t = t0 + tt;
    float x = tile[tt][lane];
    float mu = x;
#pragma unroll
    for (int m = 1; m < 64; m <<= 1) mu += __shfl_xor(mu, m);
    mu *= (1.f / 64.f);
    float d = x - mu;
    float var = d * d;
#pragma unroll
    for (int m = 1; m < 64; m <<= 1) var += __shfl_xor(var, m);
    var *= (1.f / 64.f);
    float y = d * rsqrtf(var + 6.4e-4f) * lw + lb;
    size_t off = ((size_t)(b * T_ + t)) * C_ + c;
    float bd = bf2f(rb[off]) * bf2f(kb[off]) * rk;
#pragma unroll
    for (int m = 1; m < 64; m <<= 1) bd += __shfl_xor(bd, m);
    float res = (y + bd * bf2f(vb[off])) * bf2f(g[off]);
    outg[off] = f2bf(res);
  }
}

// ---------------- host launch ----------------
extern "C" void kernel_launch(void* const* d_in, const int* in_sizes, int n_in,
                              void* d_out, int out_size, void* d_ws, size_t ws_size,
                              hipStream_t stream) {
  const float* x      = (const float*)d_in[0];
  const float* vfirst = (const float*)d_in[1];
  const float* xprev  = (const float*)d_in[2];
  const float* wkv0   = (const float*)d_in[3];
  const float* x_r = (const float*)d_in[4];
  const float* x_w = (const float*)d_in[5];
  const float* x_k = (const float*)d_in[6];
  const float* x_v = (const float*)d_in[7];
  const float* x_a = (const float*)d_in[8];
  const float* x_g = (const float*)d_in[9];
  const float* w0 = (const float*)d_in[10];
  const float* w1 = (const float*)d_in[11];
  const float* w2 = (const float*)d_in[12];
  const float* a0 = (const float*)d_in[13];
  const float* a1 = (const float*)d_in[14];
  const float* a2 = (const float*)d_in[15];
  const float* v0 = (const float*)d_in[16];
  const float* v1 = (const float*)d_in[17];
  const float* v2 = (const float*)d_in[18];
  const float* g1 = (const float*)d_in[19];
  const float* g2 = (const float*)d_in[20];
  const float* k_k = (const float*)d_in[21];
  const float* k_a = (const float*)d_in[22];
  const float* r_k = (const float*)d_in[23];
  const float* Wr = (const float*)d_in[24];
  const float* Wk = (const float*)d_in[25];
  const float* Wv = (const float*)d_in[26];
  const float* Wo = (const float*)d_in[27];
  const float* lnw = (const float*)d_in[28];
  const float* lnb = (const float*)d_in[29];
  float* out = (float*)d_out;
  char* ws = (char*)d_ws;

  // ---- workspace layout (~239 MiB + pad) ----
  size_t woff = 0;
  auto alloc = [&](size_t n) { char* p = ws + woff; woff += n; return p; };
  char* R1 = alloc(67108864);                       // ABF|SVB -> WD (f32)
  unsigned short* ABF = (unsigned short*)R1;
  unsigned short* SVB = (unsigned short*)(R1 + 33554432);
  float* WD = (float*)R1;
  unsigned short* WT  = (unsigned short*)alloc(8388608);   // transposed big weight
  unsigned short* W1T = (unsigned short*)alloc(262144);
  unsigned short* A1T = (unsigned short*)alloc(262144);
  unsigned short* V1T = (unsigned short*)alloc(131072);
  unsigned short* G1T = (unsigned short*)alloc(524288);
  unsigned short* W2T = (unsigned short*)alloc(262144);
  unsigned short* A2T = (unsigned short*)alloc(262144);
  unsigned short* V2T = (unsigned short*)alloc(131072);
  unsigned short* G2T = (unsigned short*)alloc(524288);
  unsigned short* HWB = (unsigned short*)alloc(1048576);
  unsigned short* HAB = (unsigned short*)alloc(1048576);
  unsigned short* HVB = (unsigned short*)alloc(524288);
  unsigned short* HGB = (unsigned short*)alloc(2097152);
  unsigned short* RB  = (unsigned short*)alloc(33554432);
  unsigned short* KB  = (unsigned short*)alloc(33554432);
  unsigned short* VB  = (unsigned short*)alloc(33554432);
  unsigned short* AHB = (unsigned short*)alloc(33554432);
  unsigned short* BHB = (unsigned short*)alloc(33554432);
  alloc(65536);  // safety pad
  // Temporal overlays (regions dead at the time of each use):
  unsigned short* XMr = VB;                   // dead once V-GEMM writes VB
  unsigned short* XMv = KB;                   // dead once K-GEMM writes KB
  unsigned short* XMk = (unsigned short*)out; // d_out free until scan writes out_tr
  float* OUT_TR = out;                        // scan output, consumed by k_gn_t
  unsigned short* GBF  = AHB;                 // post-scan overlay (AHB dead)
  unsigned short* OUTG = BHB;                 // post-scan overlay (BHB dead)

  dim3 blk(256);
  dim3 gg(16, 64);
  dim3 g1d(1024);

  // small weight transposes (K-contiguous layouts)
  k_transpose<<<dim3(2, 64), blk, 0, stream>>>(w1, W1T, 2048, 64);
  k_transpose<<<dim3(2, 64), blk, 0, stream>>>(a1, A1T, 2048, 64);
  k_transpose<<<dim3(1, 64), blk, 0, stream>>>(v1, V1T, 2048, 32);
  k_transpose<<<dim3(4, 64), blk, 0, stream>>>(g1, G1T, 2048, 128);
  k_transpose<<<dim3(64, 2), blk, 0, stream>>>(w2, W2T, 64, 2048);
  k_transpose<<<dim3(64, 2), blk, 0, stream>>>(a2, A2T, 64, 2048);
  k_transpose<<<dim3(64, 1), blk, 0, stream>>>(v2, V2T, 32, 2048);
  k_transpose<<<dim3(64, 4), blk, 0, stream>>>(g2, G2T, 128, 2048);

  // mix prep: x read once -> r/v/k mixes (XMk parked in d_out)
  k_prep3<<<dim3(M_), blk, 0, stream>>>(x, xprev, x_r, x_v, x_k, XMr, XMv, XMk);

  // merged down-GEMMs (w,a,v,g)
  k_down4<<<dim3(256), blk, 0, stream>>>(x, xprev, XMv, x_w, x_a, x_g,
                                         W1T, A1T, V1T, G1T, HWB, HAB, HVB, HGB);

  // up-GEMMs needed before projections
  k_up<64, 1><<<gg, blk, 0, stream>>>(HAB, A2T, a0, nullptr, ABF);
  k_up<32, 1><<<gg, blk, 0, stream>>>(HVB, V2T, v0, nullptr, SVB);

  // R projection (XMr in VB region)
  k_transpose<<<dim3(64, 64), blk, 0, stream>>>(Wr, WT, 2048, 2048);
  k_gemm_big<0><<<g1d, blk, 0, stream>>>(XMr, WT,
      nullptr, RB, nullptr, nullptr, nullptr, nullptr, nullptr, nullptr, nullptr);

  // V projection (reads XMv from KB region + SVB; writes VB, killing XMr)
  k_transpose<<<dim3(64, 64), blk, 0, stream>>>(Wv, WT, 2048, 2048);
  k_gemm_big<1><<<g1d, blk, 0, stream>>>(XMv, WT,
      nullptr, VB, SVB, vfirst, nullptr, nullptr, nullptr, nullptr, nullptr);

  // K projection (reads XMk from d_out; writes KB killing XMv, + AHB/BHB)
  k_transpose<<<dim3(64, 64), blk, 0, stream>>>(Wk, WT, 2048, 2048);
  k_gemm_big<2><<<g1d, blk, 0, stream>>>(XMk, WT,
      nullptr, KB, nullptr, nullptr, ABF, k_k, k_a, AHB, BHB);

  // w-chain up (WD overlays ABF+SVB, both consumed)
  k_up<64, 0><<<gg, blk, 0, stream>>>(HWB, W2T, w0, WD, nullptr);

  // recurrent scan -> out_tr in d_out (XMk already consumed)
  k_scan<<<dim3(1024), dim3(64), 0, stream>>>(RB, WD, KB, VB, AHB, BHB, wkv0, OUT_TR);

  // g-chain up (GBF overlays AHB)
  k_up<128, 3><<<gg, blk, 0, stream>>>(HGB, G2T, nullptr, nullptr, GBF);

  // GroupNorm + bonus + gate (OUTG overlays BHB)
  k_gn_t<<<dim3(4096), blk, 0, stream>>>(OUT_TR, RB, KB, VB, GBF, r_k, lnw, lnb, OUTG);

  // final projection (overwrites d_out with the real output)
  k_transpose<<<dim3(64, 64), blk, 0, stream>>>(Wo, WT, 2048, 2048);
  k_gemm_big<3><<<g1d, blk, 0, stream>>>(OUTG, WT,
      out, nullptr, nullptr, nullptr, nullptr, nullptr, nullptr, nullptr, nullptr);
}

// Round 8
// 1410.685 us; speedup vs baseline: 1.5356x; 1.5356x over previous
//
#include <hip/hip_runtime.h>

typedef float f32x4 __attribute__((ext_vector_type(4)));
typedef __bf16 bf16x8 __attribute__((ext_vector_type(8)));
typedef unsigned int u32x4 __attribute__((ext_vector_type(4)));

#define DI __device__ __forceinline__

constexpr int B_ = 4, T_ = 2048, C_ = 2048, H_ = 32;
constexpr int M_ = B_ * T_;  // 8192 rows

DI unsigned short f2bf(float f) {
  unsigned u = __float_as_uint(f);
  return (unsigned short)((u + 0x7FFFu + ((u >> 16) & 1u)) >> 16);
}
DI float bf2f(unsigned short h) { return __uint_as_float(((unsigned)h) << 16); }

DI void gl16(const void* g, void* l) {
  __builtin_amdgcn_global_load_lds(
      (__attribute__((address_space(1))) const unsigned int*)g,
      (__attribute__((address_space(3))) unsigned int*)l, 16, 0, 0);
}

// quad (4-lane) sum via DPP: all 4 lanes of each quad end with the quad total
DI float qsum(float x) {
  int t = __builtin_amdgcn_update_dpp(0, __float_as_int(x), 0xB1, 0xF, 0xF, true);
  x += __int_as_float(t);
  t = __builtin_amdgcn_update_dpp(0, __float_as_int(x), 0x4E, 0xF, 0xF, true);
  return x + __int_as_float(t);
}

// ---------------- transpose f32 (R x C) -> bf16 (C x R) ----------------
__global__ __launch_bounds__(256) void k_transpose(const float* __restrict__ in,
                                                   unsigned short* __restrict__ out,
                                                   int R, int C) {
  __shared__ float tile[32][33];
  int c0 = blockIdx.x * 32, r0 = blockIdx.y * 32;
  int tx = threadIdx.x & 31, ty = threadIdx.x >> 5;
#pragma unroll
  for (int i = 0; i < 4; ++i) {
    int r = r0 + ty * 4 + i, c = c0 + tx;
    if (r < R && c < C) tile[ty * 4 + i][tx] = in[(size_t)r * C + c];
  }
  __syncthreads();
#pragma unroll
  for (int i = 0; i < 4; ++i) {
    int c = c0 + ty * 4 + i, r = r0 + tx;
    if (r < R && c < C) out[(size_t)c * R + r] = f2bf(tile[tx][ty * 4 + i]);
  }
}

// ---------------- token-shift mix prep: 3 coef sets, x read once ----------------
DI void mix_emit(const float* coef, int c0, size_t off,
                 const float* xv, const float* dx, unsigned short* dst) {
  unsigned short u[8];
#pragma unroll
  for (int i = 0; i < 2; ++i) {
    f32x4 cf = *(const f32x4*)(coef + c0 + i * 4);
#pragma unroll
    for (int j = 0; j < 4; ++j) u[i * 4 + j] = f2bf(xv[i * 4 + j] + dx[i * 4 + j] * cf[j]);
  }
  u32x4 pv;
#pragma unroll
  for (int j = 0; j < 4; ++j) pv[j] = (unsigned)u[2 * j] | ((unsigned)u[2 * j + 1] << 16);
  *(u32x4*)(dst + off) = pv;
}

__global__ __launch_bounds__(256) void k_prep3(
    const float* __restrict__ x, const float* __restrict__ xprev,
    const float* __restrict__ cR, const float* __restrict__ cV,
    const float* __restrict__ cK,
    unsigned short* __restrict__ XR, unsigned short* __restrict__ XV,
    unsigned short* __restrict__ XK) {
  int bt = blockIdx.x;
  int t = bt & (T_ - 1);
  int c0 = threadIdx.x * 8;
  size_t off = (size_t)bt * C_ + c0;
  const float* xp = x + off;
  const float* pp = t ? (xp - C_) : (xprev + (size_t)(bt >> 11) * C_ + c0);
  float xv[8], dx[8];
#pragma unroll
  for (int i = 0; i < 2; ++i) {
    f32x4 a = *(const f32x4*)(xp + i * 4);
    f32x4 p = *(const f32x4*)(pp + i * 4);
#pragma unroll
    for (int j = 0; j < 4; ++j) { xv[i * 4 + j] = a[j]; dx[i * 4 + j] = p[j] - a[j]; }
  }
  mix_emit(cR, c0, off, xv, dx, XR);
  mix_emit(cV, c0, off, xv, dx, XV);
  mix_emit(cK, c0, off, xv, dx, XK);
}

// fused token-shift mix staging (for small down-GEMMs only)
DI void stage_mix(const float* __restrict__ x, const float* __restrict__ xprev,
                  const float* __restrict__ coef, unsigned short* As,
                  int m0, int kt, int wv, int lane) {
  const int lr = lane >> 3, lc = (lane & 7) * 8;
  f32x4 c0 = *(const f32x4*)(coef + kt + lc);
  f32x4 c1 = *(const f32x4*)(coef + kt + lc + 4);
#pragma unroll
  for (int i = 0; i < 4; ++i) {
    int chunk = wv * 4 + i;
    int r = chunk * 8 + lr;
    int m = m0 + r;
    const float* xp = x + (size_t)m * C_ + kt + lc;
    const float* pp = (m & (T_ - 1)) ? (xp - C_)
                                     : (xprev + (size_t)(m >> 11) * C_ + kt + lc);
    f32x4 xv0 = *(const f32x4*)xp, xv1 = *(const f32x4*)(xp + 4);
    f32x4 pv0 = *(const f32x4*)pp, pv1 = *(const f32x4*)(pp + 4);
    unsigned short u[8];
#pragma unroll
    for (int j = 0; j < 4; ++j) u[j] = f2bf(xv0[j] + (pv0[j] - xv0[j]) * c0[j]);
#pragma unroll
    for (int j = 0; j < 4; ++j) u[4 + j] = f2bf(xv1[j] + (pv1[j] - xv1[j]) * c1[j]);
    u32x4 pk;
#pragma unroll
    for (int j = 0; j < 4; ++j) pk[j] = (unsigned)u[2 * j] | ((unsigned)u[2 * j + 1] << 16);
    *(u32x4*)((char*)As + chunk * 1024 + lane * 16) = pk;
  }
}

// ---------------- big GEMM: 128x128 tile, K=2048, XCD-swizzled 1D grid ----------
// grid = 1024: xcd = bid&7 owns m-tiles [xcd*8, xcd*8+8) -> A-panel L2-resident.
// EPI 0: RB = bf16(acc)
// EPI 1: VB = bf16(acc + (vfirst - acc)*svb)
// EPI 2: kk-norm fused: KB, AHB, BHB
// EPI 3: f32 store (final output GEMM)
template <int EPI>
__global__ __launch_bounds__(256, 2) void k_gemm_big(
    const unsigned short* __restrict__ A,
    const unsigned short* __restrict__ Bt,
    float* __restrict__ outF, unsigned short* __restrict__ outB,
    const unsigned short* __restrict__ svb, const float* __restrict__ vfirst,
    const unsigned short* __restrict__ abf,
    const float* __restrict__ k_k, const float* __restrict__ k_a,
    unsigned short* __restrict__ ahb, unsigned short* __restrict__ bhb) {
  __shared__ __align__(16) unsigned short As[128][64];
  __shared__ __align__(16) unsigned short Bs[128][64];
  const int tid = threadIdx.x, lane = tid & 63, wv = tid >> 6;
  const int bid = blockIdx.x;
  const int loc = bid >> 3;
  const int by = (bid & 7) * 8 + (loc & 7);
  const int bx = loc >> 3;
  const int m0 = by * 128, n0 = bx * 128;
  const int wm = (wv >> 1) * 64, wn = (wv & 1) * 64;
  const int lr = lane >> 3, lc = (lane & 7) * 8;
  f32x4 acc[4][4] = {};
  for (int kt = 0; kt < C_; kt += 64) {
    __syncthreads();
#pragma unroll
    for (int i = 0; i < 4; ++i) {
      int chunk = wv * 4 + i, r = chunk * 8 + lr;
      gl16(A + (size_t)(m0 + r) * C_ + kt + lc, (char*)&As[0][0] + chunk * 1024);
      gl16(Bt + (size_t)(n0 + r) * C_ + kt + lc, (char*)&Bs[0][0] + chunk * 1024);
    }
    __syncthreads();
    const int rr = lane & 15;
#pragma unroll
    for (int kh = 0; kh < 2; ++kh) {
      const int kof = kh * 32 + (lane >> 4) * 8;
      bf16x8 af[4], bfv[4];
#pragma unroll
      for (int i = 0; i < 4; ++i) af[i] = *(const bf16x8*)&As[wm + i * 16 + rr][kof];
#pragma unroll
      for (int j = 0; j < 4; ++j) bfv[j] = *(const bf16x8*)&Bs[wn + j * 16 + rr][kof];
#pragma unroll
      for (int i = 0; i < 4; ++i)
#pragma unroll
        for (int j = 0; j < 4; ++j)
          acc[i][j] = __builtin_amdgcn_mfma_f32_16x16x32_bf16(af[i], bfv[j], acc[i][j], 0, 0, 0);
    }
  }
  const int cr = (lane >> 4) * 4, cc2 = lane & 15;
  if constexpr (EPI == 2) {
    float kkv[4], kav[4];
#pragma unroll
    for (int j = 0; j < 4; ++j) {
      int col = n0 + wn + j * 16 + cc2;
      kkv[j] = k_k[col];
      kav[j] = k_a[col];
    }
#pragma unroll
    for (int i = 0; i < 4; ++i)
#pragma unroll
      for (int q = 0; q < 4; ++q) {
        int row = m0 + wm + i * 16 + cr + q;
        float kk4[4], p = 0.f;
#pragma unroll
        for (int j = 0; j < 4; ++j) {
          float kkc = acc[i][j][q] * kkv[j];
          kk4[j] = kkc;
          p += kkc * kkc;
        }
        p += __shfl_xor(p, 1); p += __shfl_xor(p, 2);
        p += __shfl_xor(p, 4); p += __shfl_xor(p, 8);
        float inv = 1.f / fmaxf(sqrtf(p), 1e-12f);
#pragma unroll
        for (int j = 0; j < 4; ++j) {
          int col = n0 + wn + j * 16 + cc2;
          size_t off = (size_t)row * C_ + col;
          float kkn = kk4[j] * inv;
          float a = bf2f(abf[off]);
          ahb[off] = f2bf(-kkn);
          bhb[off] = f2bf(kkn * a);
          outB[off] = f2bf(acc[i][j][q] * (1.f + (a - 1.f) * kav[j]));
        }
      }
  } else {
#pragma unroll
    for (int i = 0; i < 4; ++i)
#pragma unroll
      for (int j = 0; j < 4; ++j)
#pragma unroll
        for (int q = 0; q < 4; ++q) {
          int row = m0 + wm + i * 16 + cr + q;
          int col = n0 + wn + j * 16 + cc2;
          size_t off = (size_t)row * C_ + col;
          float v = acc[i][j][q];
          if constexpr (EPI == 0) {
            outB[off] = f2bf(v);
          } else if constexpr (EPI == 1) {
            float s = bf2f(svb[off]);
            outB[off] = f2bf(v + (vfirst[off] - v) * s);
          } else {
            outF[off] = v;
          }
        }
  }
}

// ---------------- down GEMM body (shared by the merged k_down4) ----------------
template <int N, int ACT, bool FUSED>
DI void down_body(int m0, unsigned short (*As)[64], unsigned short (*Bs)[64],
                  const unsigned short* __restrict__ A,
                  const float* __restrict__ x, const float* __restrict__ xprev,
                  const float* __restrict__ coef, const unsigned short* __restrict__ Bt,
                  unsigned short* __restrict__ out) {
  const int tid = threadIdx.x, lane = tid & 63, wv = tid >> 6;
  const int wm = wv * 32;
  const int lr = lane >> 3, lc = (lane & 7) * 8;
  f32x4 acc[2][N / 16] = {};
  for (int kt = 0; kt < C_; kt += 64) {
    __syncthreads();
    if constexpr (FUSED) {
      stage_mix(x, xprev, coef, &As[0][0], m0, kt, wv, lane);
    } else {
#pragma unroll
      for (int i = 0; i < 4; ++i) {
        int chunk = wv * 4 + i, r = chunk * 8 + lr;
        gl16(A + (size_t)(m0 + r) * C_ + kt + lc, (char*)&As[0][0] + chunk * 1024);
      }
    }
#pragma unroll
    for (int i = 0; i < N / 32; ++i) {
      int chunk = wv * (N / 32) + i, r = chunk * 8 + lr;
      gl16(Bt + (size_t)r * C_ + kt + lc, (char*)&Bs[0][0] + chunk * 1024);
    }
    __syncthreads();
    const int rr = lane & 15;
#pragma unroll
    for (int kh = 0; kh < 2; ++kh) {
      const int kof = kh * 32 + (lane >> 4) * 8;
      bf16x8 af[2], bfv[N / 16];
#pragma unroll
      for (int i = 0; i < 2; ++i) af[i] = *(const bf16x8*)&As[wm + i * 16 + rr][kof];
#pragma unroll
      for (int j = 0; j < N / 16; ++j) bfv[j] = *(const bf16x8*)&Bs[j * 16 + rr][kof];
#pragma unroll
      for (int i = 0; i < 2; ++i)
#pragma unroll
        for (int j = 0; j < N / 16; ++j)
          acc[i][j] = __builtin_amdgcn_mfma_f32_16x16x32_bf16(af[i], bfv[j], acc[i][j], 0, 0, 0);
    }
  }
  const int cr = (lane >> 4) * 4, cc2 = lane & 15;
#pragma unroll
  for (int i = 0; i < 2; ++i)
#pragma unroll
    for (int j = 0; j < N / 16; ++j)
#pragma unroll
      for (int q = 0; q < 4; ++q) {
        int row = m0 + wm + i * 16 + cr + q;
        int col = j * 16 + cc2;
        float v = acc[i][j][q];
        if (ACT == 1) v = tanhf(v);
        else if (ACT == 2) v = 1.f / (1.f + expf(-v));
        out[(size_t)row * N + col] = f2bf(v);
      }
}

// merged down-GEMMs: 256 blocks (4 groups x 64 m-tiles)
__global__ __launch_bounds__(256, 2) void k_down4(
    const float* __restrict__ x, const float* __restrict__ xprev,
    const unsigned short* __restrict__ XMv,
    const float* __restrict__ xw, const float* __restrict__ xa,
    const float* __restrict__ xg,
    const unsigned short* __restrict__ W1T, const unsigned short* __restrict__ A1T,
    const unsigned short* __restrict__ V1T, const unsigned short* __restrict__ G1T,
    unsigned short* __restrict__ HWB, unsigned short* __restrict__ HAB,
    unsigned short* __restrict__ HVB, unsigned short* __restrict__ HGB) {
  __shared__ __align__(16) unsigned short As[128][64];
  __shared__ __align__(16) unsigned short Bs[128][64];
  int g = blockIdx.x >> 6;
  int m0 = (blockIdx.x & 63) * 128;
  if (g == 0)      down_body<64, 1, true>(m0, As, Bs, nullptr, x, xprev, xw, W1T, HWB);
  else if (g == 1) down_body<64, 0, true>(m0, As, Bs, nullptr, x, xprev, xa, A1T, HAB);
  else if (g == 2) down_body<32, 0, false>(m0, As, Bs, XMv, nullptr, nullptr, nullptr, V1T, HVB);
  else             down_body<128, 2, true>(m0, As, Bs, nullptr, x, xprev, xg, G1T, HGB);
}

// ---------------- up GEMM (K in {32,64,128}), single K pass ----------------
// MODE 0: wd = exp(-exp(-softplus(-(bias+up)) - 0.5)) -> outF (f32)
// MODE 1: sigmoid(bias+up) -> outB (bf16)
// MODE 3: up -> outB (bf16)
template <int K, int MODE>
__global__ __launch_bounds__(256, 2) void k_up(
    const unsigned short* __restrict__ A, const unsigned short* __restrict__ Bt,
    const float* __restrict__ bias, float* __restrict__ outF,
    unsigned short* __restrict__ outB) {
  __shared__ __align__(16) unsigned short As[128][K];
  __shared__ __align__(16) unsigned short Bs[128][K];
  const int tid = threadIdx.x, lane = tid & 63, wv = tid >> 6;
  const int m0 = blockIdx.y * 128, n0 = blockIdx.x * 128;
  const int wm = (wv >> 1) * 64, wn = (wv & 1) * 64;
  constexpr int LPR = K / 8;
  constexpr int RPC = 64 / LPR;
  const int lr = lane / LPR, lc = (lane % LPR) * 8;
  f32x4 acc[4][4] = {};
#pragma unroll
  for (int i = 0; i < K / 16; ++i) {
    int chunk = wv * (K / 16) + i;
    int r = chunk * RPC + lr;
    gl16(A + (size_t)(m0 + r) * K + lc, (char*)&As[0][0] + chunk * 1024);
    gl16(Bt + (size_t)(n0 + r) * K + lc, (char*)&Bs[0][0] + chunk * 1024);
  }
  __syncthreads();
  const int rr = lane & 15;
#pragma unroll
  for (int ks = 0; ks < K / 32; ++ks) {
    const int kof = ks * 32 + (lane >> 4) * 8;
    bf16x8 af[4], bfv[4];
#pragma unroll
    for (int i = 0; i < 4; ++i) af[i] = *(const bf16x8*)&As[wm + i * 16 + rr][kof];
#pragma unroll
    for (int j = 0; j < 4; ++j) bfv[j] = *(const bf16x8*)&Bs[wn + j * 16 + rr][kof];
#pragma unroll
    for (int i = 0; i < 4; ++i)
#pragma unroll
      for (int j = 0; j < 4; ++j)
        acc[i][j] = __builtin_amdgcn_mfma_f32_16x16x32_bf16(af[i], bfv[j], acc[i][j], 0, 0, 0);
  }
  const int cr = (lane >> 4) * 4, cc2 = lane & 15;
#pragma unroll
  for (int i = 0; i < 4; ++i)
#pragma unroll
    for (int j = 0; j < 4; ++j)
#pragma unroll
      for (int q = 0; q < 4; ++q) {
        int row = m0 + wm + i * 16 + cr + q;
        int col = n0 + wn + j * 16 + cc2;
        size_t off = (size_t)row * C_ + col;
        float up = acc[i][j][q];
        if (MODE == 0) {
          float z = -(bias[col] + up);
          float sp = fmaxf(z, 0.f) + log1pf(expf(-fabsf(z)));
          outF[off] = expf(-expf(-sp - 0.5f));
        } else if (MODE == 1) {
          outB[off] = f2bf(1.f / (1.f + expf(-(bias[col] + up))));
        } else {
          outB[off] = f2bf(up);
        }
      }
}

// ---------------- WKV recurrent scan: register-only, no barriers ----------------
// EXACT Round-2 structure (benched 689 us in R3). 1024 one-wave blocks.
// Block p: wr = p>>7 (row-octet), bh = p&127. Lane: rl = lane>>3 (local row),
// e = lane&7 (elem octet). State: 8 f32/lane. 4 named register slots, depth-3
// prefetch, compiler-managed waitcnts, per-step predicated store.
__global__ __launch_bounds__(64) void k_scan(
    const unsigned short* __restrict__ RB, const float* __restrict__ WD,
    const unsigned short* __restrict__ KB, const unsigned short* __restrict__ VB,
    const unsigned short* __restrict__ AHB, const unsigned short* __restrict__ BHB,
    const float* __restrict__ s0, float* __restrict__ out) {
  const int lane = threadIdx.x & 63;
  const int p = blockIdx.x;
  const int wr = p >> 7, bh = p & 127;
  const int b = bh >> 5, h = bh & 31;
  const int e = lane & 7, rl = lane >> 3;
  const int row = wr * 8 + rl;
  const int e8 = e * 8;
  const size_t base = (size_t)b * T_ * C_ + h * 64;  // elem offset at t=0
  float S[8];
  {
    const float* sp = s0 + ((size_t)(b * H_ + h) * 64 + row) * 64 + e8;
    f32x4 s0v = *(const f32x4*)sp, s1v = *(const f32x4*)(sp + 4);
#pragma unroll
    for (int j = 0; j < 4; ++j) { S[j] = s0v[j]; S[4 + j] = s1v[j]; }
  }

#define DECL_SLOT(n) bf16x8 r##n, k##n, a##n, bb##n; f32x4 wA##n, wB##n; unsigned short v##n;
  DECL_SLOT(0) DECL_SLOT(1) DECL_SLOT(2) DECL_SLOT(3)

#define ISSUE(n, t)                                              \
  {                                                              \
    int ti = (t) < T_ ? (t) : T_ - 1;                            \
    size_t eo = base + (size_t)ti * C_;                          \
    size_t ee = eo + e8;                                         \
    r##n = *(const bf16x8*)(RB + ee);                            \
    k##n = *(const bf16x8*)(KB + ee);                            \
    a##n = *(const bf16x8*)(AHB + ee);                           \
    bb##n = *(const bf16x8*)(BHB + ee);                          \
    wA##n = *(const f32x4*)(WD + ee);                            \
    wB##n = *(const f32x4*)(WD + ee + 4);                        \
    v##n = VB[eo + row];                                         \
  }

#define STEP(n, t)                                               \
  {                                                              \
    float rr[8], kk[8], aa[8], bv[8], ww[8];                     \
    _Pragma("unroll") for (int j = 0; j < 8; ++j) {              \
      rr[j] = (float)r##n[j];                                    \
      kk[j] = (float)k##n[j];                                    \
      aa[j] = (float)a##n[j];                                    \
      bv[j] = (float)bb##n[j];                                   \
    }                                                            \
    _Pragma("unroll") for (int j = 0; j < 4; ++j) {              \
      ww[j] = wA##n[j];                                          \
      ww[4 + j] = wB##n[j];                                      \
    }                                                            \
    float sa0 = S[0] * aa[0], sa1 = S[1] * aa[1];                \
    _Pragma("unroll") for (int j = 2; j < 8; j += 2) {           \
      sa0 = fmaf(S[j], aa[j], sa0);                              \
      sa1 = fmaf(S[j + 1], aa[j + 1], sa1);                      \
    }                                                            \
    float sa = qsum(sa0 + sa1);                                  \
    sa += __shfl_xor(sa, 4);                                     \
    float vi = bf2f(v##n);                                       \
    float o0 = 0.f, o1 = 0.f;                                    \
    _Pragma("unroll") for (int j = 0; j < 8; j += 2) {           \
      S[j] = fmaf(S[j], ww[j], fmaf(sa, bv[j], vi * kk[j]));     \
      S[j + 1] = fmaf(S[j + 1], ww[j + 1],                       \
                      fmaf(sa, bv[j + 1], vi * kk[j + 1]));      \
      o0 = fmaf(S[j], rr[j], o0);                                \
      o1 = fmaf(S[j + 1], rr[j + 1], o1);                        \
    }                                                            \
    float o = qsum(o0 + o1);                                     \
    o += __shfl_xor(o, 4);                                       \
    if (e == 0) out[base + (size_t)(t) * C_ + row] = o;          \
  }

  ISSUE(0, 0) ISSUE(1, 1) ISSUE(2, 2)
#pragma unroll 1
  for (int t = 0; t < T_; t += 4) {
    ISSUE(3, t + 3) STEP(0, t)
    ISSUE(0, t + 4) STEP(1, t + 1)
    ISSUE(1, t + 5) STEP(2, t + 2)
    ISSUE(2, t + 6) STEP(3, t + 3)
  }
#undef DECL_SLOT
#undef ISSUE
#undef STEP
}

// ---------------- GroupNorm + bonus + gate (wave per (b,t,h)) ----------------
__global__ __launch_bounds__(256) void k_gn(
    const float* __restrict__ o, const unsigned short* __restrict__ rb,
    const unsigned short* __restrict__ kb, const unsigned short* __restrict__ v,
    const unsigned short* __restrict__ g, const float* __restrict__ r_k,
    const float* __restrict__ lnw, const float* __restrict__ lnb,
    unsigned short* __restrict__ outg) {
  int wid = blockIdx.x * 4 + (threadIdx.x >> 6);
  int lane = threadIdx.x & 63;
  int h = wid & (H_ - 1);
  size_t bt = (size_t)(wid >> 5);
  size_t off = bt * C_ + h * 64 + lane;
  int c = h * 64 + lane;
  float x = o[off];
  float mu = x;
#pragma unroll
  for (int m = 1; m < 64; m <<= 1) mu += __shfl_xor(mu, m);
  mu *= (1.f / 64.f);
  float d = x - mu;
  float var = d * d;
#pragma unroll
  for (int m = 1; m < 64; m <<= 1) var += __shfl_xor(var, m);
  var *= (1.f / 64.f);
  float y = d * rsqrtf(var + 6.4e-4f) * lnw[c] + lnb[c];
  float bd = bf2f(rb[off]) * bf2f(kb[off]) * r_k[c];
#pragma unroll
  for (int m = 1; m < 64; m <<= 1) bd += __shfl_xor(bd, m);
  float res = (y + bd * bf2f(v[off])) * bf2f(g[off]);
  outg[off] = f2bf(res);
}

// ---------------- host launch ----------------
extern "C" void kernel_launch(void* const* d_in, const int* in_sizes, int n_in,
                              void* d_out, int out_size, void* d_ws, size_t ws_size,
                              hipStream_t stream) {
  const float* x      = (const float*)d_in[0];
  const float* vfirst = (const float*)d_in[1];
  const float* xprev  = (const float*)d_in[2];
  const float* wkv0   = (const float*)d_in[3];
  const float* x_r = (const float*)d_in[4];
  const float* x_w = (const float*)d_in[5];
  const float* x_k = (const float*)d_in[6];
  const float* x_v = (const float*)d_in[7];
  const float* x_a = (const float*)d_in[8];
  const float* x_g = (const float*)d_in[9];
  const float* w0 = (const float*)d_in[10];
  const float* w1 = (const float*)d_in[11];
  const float* w2 = (const float*)d_in[12];
  const float* a0 = (const float*)d_in[13];
  const float* a1 = (const float*)d_in[14];
  const float* a2 = (const float*)d_in[15];
  const float* v0 = (const float*)d_in[16];
  const float* v1 = (const float*)d_in[17];
  const float* v2 = (const float*)d_in[18];
  const float* g1 = (const float*)d_in[19];
  const float* g2 = (const float*)d_in[20];
  const float* k_k = (const float*)d_in[21];
  const float* k_a = (const float*)d_in[22];
  const float* r_k = (const float*)d_in[23];
  const float* Wr = (const float*)d_in[24];
  const float* Wk = (const float*)d_in[25];
  const float* Wv = (const float*)d_in[26];
  const float* Wo = (const float*)d_in[27];
  const float* lnw = (const float*)d_in[28];
  const float* lnb = (const float*)d_in[29];
  float* out = (float*)d_out;
  char* ws = (char*)d_ws;

  // ---- workspace layout (~239 MiB + pad) ----
  size_t woff = 0;
  auto alloc = [&](size_t n) { char* p = ws + woff; woff += n; return p; };
  char* R1 = alloc(67108864);                       // ABF|SVB -> WD (f32)
  unsigned short* ABF = (unsigned short*)R1;
  unsigned short* SVB = (unsigned short*)(R1 + 33554432);
  float* WD = (float*)R1;
  unsigned short* WT  = (unsigned short*)alloc(8388608);   // transposed big weight
  unsigned short* W1T = (unsigned short*)alloc(262144);
  unsigned short* A1T = (unsigned short*)alloc(262144);
  unsigned short* V1T = (unsigned short*)alloc(131072);
  unsigned short* G1T = (unsigned short*)alloc(524288);
  unsigned short* W2T = (unsigned short*)alloc(262144);
  unsigned short* A2T = (unsigned short*)alloc(262144);
  unsigned short* V2T = (unsigned short*)alloc(131072);
  unsigned short* G2T = (unsigned short*)alloc(524288);
  unsigned short* HWB = (unsigned short*)alloc(1048576);
  unsigned short* HAB = (unsigned short*)alloc(1048576);
  unsigned short* HVB = (unsigned short*)alloc(524288);
  unsigned short* HGB = (unsigned short*)alloc(2097152);
  unsigned short* RB  = (unsigned short*)alloc(33554432);
  unsigned short* KB  = (unsigned short*)alloc(33554432);
  unsigned short* VB  = (unsigned short*)alloc(33554432);
  unsigned short* AHB = (unsigned short*)alloc(33554432);
  unsigned short* BHB = (unsigned short*)alloc(33554432);
  alloc(65536);  // safety pad
  // Temporal overlays (regions dead at the time of each use):
  unsigned short* XMr = VB;                   // dead once V-GEMM writes VB
  unsigned short* XMv = KB;                   // dead once K-GEMM writes KB
  unsigned short* XMk = (unsigned short*)out; // d_out free until scan writes out
  unsigned short* GBF  = AHB;                 // post-scan overlay (AHB dead)
  unsigned short* OUTG = BHB;                 // post-scan overlay (BHB dead)

  dim3 blk(256);
  dim3 gg(16, 64);
  dim3 g1d(1024);

  // small weight transposes (K-contiguous layouts)
  k_transpose<<<dim3(2, 64), blk, 0, stream>>>(w1, W1T, 2048, 64);
  k_transpose<<<dim3(2, 64), blk, 0, stream>>>(a1, A1T, 2048, 64);
  k_transpose<<<dim3(1, 64), blk, 0, stream>>>(v1, V1T, 2048, 32);
  k_transpose<<<dim3(4, 64), blk, 0, stream>>>(g1, G1T, 2048, 128);
  k_transpose<<<dim3(64, 2), blk, 0, stream>>>(w2, W2T, 64, 2048);
  k_transpose<<<dim3(64, 2), blk, 0, stream>>>(a2, A2T, 64, 2048);
  k_transpose<<<dim3(64, 1), blk, 0, stream>>>(v2, V2T, 32, 2048);
  k_transpose<<<dim3(64, 4), blk, 0, stream>>>(g2, G2T, 128, 2048);

  // mix prep: x read once -> r/v/k mixes (XMk parked in d_out)
  k_prep3<<<dim3(M_), blk, 0, stream>>>(x, xprev, x_r, x_v, x_k, XMr, XMv, XMk);

  // merged down-GEMMs (w,a,v,g)
  k_down4<<<dim3(256), blk, 0, stream>>>(x, xprev, XMv, x_w, x_a, x_g,
                                         W1T, A1T, V1T, G1T, HWB, HAB, HVB, HGB);

  // up-GEMMs needed before projections
  k_up<64, 1><<<gg, blk, 0, stream>>>(HAB, A2T, a0, nullptr, ABF);
  k_up<32, 1><<<gg, blk, 0, stream>>>(HVB, V2T, v0, nullptr, SVB);

  // R projection (XMr in VB region)
  k_transpose<<<dim3(64, 64), blk, 0, stream>>>(Wr, WT, 2048, 2048);
  k_gemm_big<0><<<g1d, blk, 0, stream>>>(XMr, WT,
      nullptr, RB, nullptr, nullptr, nullptr, nullptr, nullptr, nullptr, nullptr);

  // V projection (reads XMv from KB region + SVB; writes VB, killing XMr)
  k_transpose<<<dim3(64, 64), blk, 0, stream>>>(Wv, WT, 2048, 2048);
  k_gemm_big<1><<<g1d, blk, 0, stream>>>(XMv, WT,
      nullptr, VB, SVB, vfirst, nullptr, nullptr, nullptr, nullptr, nullptr);

  // K projection (reads XMk from d_out; writes KB killing XMv, + AHB/BHB)
  k_transpose<<<dim3(64, 64), blk, 0, stream>>>(Wk, WT, 2048, 2048);
  k_gemm_big<2><<<g1d, blk, 0, stream>>>(XMk, WT,
      nullptr, KB, nullptr, nullptr, ABF, k_k, k_a, AHB, BHB);

  // w-chain up (WD overlays ABF+SVB, both consumed)
  k_up<64, 0><<<gg, blk, 0, stream>>>(HWB, W2T, w0, WD, nullptr);

  // recurrent scan -> out[b,t,c] f32 in d_out (XMk already consumed)
  k_scan<<<dim3(1024), dim3(64), 0, stream>>>(RB, WD, KB, VB, AHB, BHB, wkv0, out);

  // g-chain up (GBF overlays AHB)
  k_up<128, 3><<<gg, blk, 0, stream>>>(HGB, G2T, nullptr, nullptr, GBF);

  // GroupNorm + bonus + gate (OUTG overlays BHB)
  k_gn<<<dim3(65536), blk, 0, stream>>>(out, RB, KB, VB, GBF, r_k, lnw, lnb, OUTG);

  // final projection (overwrites d_out with the real output)
  k_transpose<<<dim3(64, 64), blk, 0, stream>>>(Wo, WT, 2048, 2048);
  k_gemm_big<3><<<g1d, blk, 0, stream>>>(OUTG, WT,
      out, nullptr, nullptr, nullptr, nullptr, nullptr, nullptr, nullptr, nullptr);
}

// Round 9
// 1360.621 us; speedup vs baseline: 1.5921x; 1.0368x over previous
//
#include <hip/hip_runtime.h>

typedef float f32x4 __attribute__((ext_vector_type(4)));
typedef __bf16 bf16x8 __attribute__((ext_vector_type(8)));
typedef unsigned int u32x4 __attribute__((ext_vector_type(4)));

#define DI __device__ __forceinline__

constexpr int B_ = 4, T_ = 2048, C_ = 2048, H_ = 32;
constexpr int M_ = B_ * T_;  // 8192 rows

DI unsigned short f2bf(float f) {
  unsigned u = __float_as_uint(f);
  return (unsigned short)((u + 0x7FFFu + ((u >> 16) & 1u)) >> 16);
}
DI float bf2f(unsigned short h) { return __uint_as_float(((unsigned)h) << 16); }

DI void gl16(const void* g, void* l) {
  __builtin_amdgcn_global_load_lds(
      (__attribute__((address_space(1))) const unsigned int*)g,
      (__attribute__((address_space(3))) unsigned int*)l, 16, 0, 0);
}

// 8-lane sum, pure DPP: quad_perm(xor1), quad_perm(xor2), row_half_mirror.
// All 8 lanes of each aligned 8-lane group end with the group total.
// (Correctness proven in R7's passing run.)
DI float rsum8(float x) {
  int t = __builtin_amdgcn_update_dpp(0, __float_as_int(x), 0xB1, 0xF, 0xF, true);
  x += __int_as_float(t);
  t = __builtin_amdgcn_update_dpp(0, __float_as_int(x), 0x4E, 0xF, 0xF, true);
  x += __int_as_float(t);
  t = __builtin_amdgcn_update_dpp(0, __float_as_int(x), 0x141, 0xF, 0xF, true);
  x += __int_as_float(t);
  return x;
}

// ---------------- transpose f32 (R x C) -> bf16 (C x R) ----------------
DI void tr_body(const float* __restrict__ in, unsigned short* __restrict__ out,
                int R, int C, int bx, int by, float (*tile)[33]) {
  int c0 = bx * 32, r0 = by * 32;
  int tx = threadIdx.x & 31, ty = threadIdx.x >> 5;
#pragma unroll
  for (int i = 0; i < 4; ++i) {
    int r = r0 + ty * 4 + i, c = c0 + tx;
    if (r < R && c < C) tile[ty * 4 + i][tx] = in[(size_t)r * C + c];
  }
  __syncthreads();
#pragma unroll
  for (int i = 0; i < 4; ++i) {
    int c = c0 + ty * 4 + i, r = r0 + tx;
    if (r < R && c < C) out[(size_t)c * R + r] = f2bf(tile[tx][ty * 4 + i]);
  }
}

__global__ __launch_bounds__(256) void k_transpose(const float* __restrict__ in,
                                                   unsigned short* __restrict__ out,
                                                   int R, int C) {
  __shared__ float tile[32][33];
  tr_body(in, out, R, C, blockIdx.x, blockIdx.y, tile);
}

// all 8 small weight transposes in one launch (1152 blocks)
__global__ __launch_bounds__(256) void k_transpose8(
    const float* w1, unsigned short* W1T, const float* a1, unsigned short* A1T,
    const float* v1, unsigned short* V1T, const float* g1, unsigned short* G1T,
    const float* w2, unsigned short* W2T, const float* a2, unsigned short* A2T,
    const float* v2, unsigned short* V2T, const float* g2, unsigned short* G2T) {
  __shared__ float tile[32][33];
  int b = blockIdx.x;
  if (b < 128)       tr_body(w1, W1T, 2048, 64, b % 2, b / 2, tile);
  else if (b < 256)  { b -= 128; tr_body(a1, A1T, 2048, 64, b % 2, b / 2, tile); }
  else if (b < 320)  { b -= 256; tr_body(v1, V1T, 2048, 32, 0, b, tile); }
  else if (b < 576)  { b -= 320; tr_body(g1, G1T, 2048, 128, b % 4, b / 4, tile); }
  else if (b < 704)  { b -= 576; tr_body(w2, W2T, 64, 2048, b % 64, b / 64, tile); }
  else if (b < 832)  { b -= 704; tr_body(a2, A2T, 64, 2048, b % 64, b / 64, tile); }
  else if (b < 896)  { b -= 832; tr_body(v2, V2T, 32, 2048, b % 64, b / 64, tile); }
  else               { b -= 896; tr_body(g2, G2T, 128, 2048, b % 64, b / 64, tile); }
}

// ---------------- token-shift mix prep: all 6 coef sets, x read once ----------
DI void mix_emit(const float* coef, int c0, size_t off,
                 const float* xv, const float* dx, unsigned short* dst) {
  unsigned short u[8];
#pragma unroll
  for (int i = 0; i < 2; ++i) {
    f32x4 cf = *(const f32x4*)(coef + c0 + i * 4);
#pragma unroll
    for (int j = 0; j < 4; ++j) u[i * 4 + j] = f2bf(xv[i * 4 + j] + dx[i * 4 + j] * cf[j]);
  }
  u32x4 pv;
#pragma unroll
  for (int j = 0; j < 4; ++j) pv[j] = (unsigned)u[2 * j] | ((unsigned)u[2 * j + 1] << 16);
  *(u32x4*)(dst + off) = pv;
}

__global__ __launch_bounds__(256) void k_prep6(
    const float* __restrict__ x, const float* __restrict__ xprev,
    const float* __restrict__ cR, const float* __restrict__ cV,
    const float* __restrict__ cK, const float* __restrict__ cW,
    const float* __restrict__ cA, const float* __restrict__ cG,
    unsigned short* __restrict__ XR, unsigned short* __restrict__ XV,
    unsigned short* __restrict__ XK, unsigned short* __restrict__ XW,
    unsigned short* __restrict__ XA, unsigned short* __restrict__ XG) {
  int bt = blockIdx.x;
  int t = bt & (T_ - 1);
  int c0 = threadIdx.x * 8;
  size_t off = (size_t)bt * C_ + c0;
  const float* xp = x + off;
  const float* pp = t ? (xp - C_) : (xprev + (size_t)(bt >> 11) * C_ + c0);
  float xv[8], dx[8];
#pragma unroll
  for (int i = 0; i < 2; ++i) {
    f32x4 a = *(const f32x4*)(xp + i * 4);
    f32x4 p = *(const f32x4*)(pp + i * 4);
#pragma unroll
    for (int j = 0; j < 4; ++j) { xv[i * 4 + j] = a[j]; dx[i * 4 + j] = p[j] - a[j]; }
  }
  mix_emit(cR, c0, off, xv, dx, XR);
  mix_emit(cV, c0, off, xv, dx, XV);
  mix_emit(cK, c0, off, xv, dx, XK);
  mix_emit(cW, c0, off, xv, dx, XW);
  mix_emit(cA, c0, off, xv, dx, XA);
  mix_emit(cG, c0, off, xv, dx, XG);
}

// ---------------- big GEMM: 128x128 tile, K=2048, XCD-swizzled 1D grid ----------
// grid = 1024: xcd = bid&7 owns m-tiles [xcd*8, xcd*8+8) -> A-panel L2-resident.
// EPI 0: RB = bf16(acc)
// EPI 1: VB = bf16(acc + (vfirst - acc)*svb)
// EPI 2: kk-norm fused: KB, AHB, BHB
// EPI 3: f32 store (final output GEMM)
template <int EPI>
__global__ __launch_bounds__(256, 2) void k_gemm_big(
    const unsigned short* __restrict__ A,
    const unsigned short* __restrict__ Bt,
    float* __restrict__ outF, unsigned short* __restrict__ outB,
    const unsigned short* __restrict__ svb, const float* __restrict__ vfirst,
    const unsigned short* __restrict__ abf,
    const float* __restrict__ k_k, const float* __restrict__ k_a,
    unsigned short* __restrict__ ahb, unsigned short* __restrict__ bhb) {
  __shared__ __align__(16) unsigned short As[128][64];
  __shared__ __align__(16) unsigned short Bs[128][64];
  const int tid = threadIdx.x, lane = tid & 63, wv = tid >> 6;
  const int bid = blockIdx.x;
  const int loc = bid >> 3;
  const int by = (bid & 7) * 8 + (loc & 7);
  const int bx = loc >> 3;
  const int m0 = by * 128, n0 = bx * 128;
  const int wm = (wv >> 1) * 64, wn = (wv & 1) * 64;
  const int lr = lane >> 3, lc = (lane & 7) * 8;
  f32x4 acc[4][4] = {};
  for (int kt = 0; kt < C_; kt += 64) {
    __syncthreads();
#pragma unroll
    for (int i = 0; i < 4; ++i) {
      int chunk = wv * 4 + i, r = chunk * 8 + lr;
      gl16(A + (size_t)(m0 + r) * C_ + kt + lc, (char*)&As[0][0] + chunk * 1024);
      gl16(Bt + (size_t)(n0 + r) * C_ + kt + lc, (char*)&Bs[0][0] + chunk * 1024);
    }
    __syncthreads();
    const int rr = lane & 15;
#pragma unroll
    for (int kh = 0; kh < 2; ++kh) {
      const int kof = kh * 32 + (lane >> 4) * 8;
      bf16x8 af[4], bfv[4];
#pragma unroll
      for (int i = 0; i < 4; ++i) af[i] = *(const bf16x8*)&As[wm + i * 16 + rr][kof];
#pragma unroll
      for (int j = 0; j < 4; ++j) bfv[j] = *(const bf16x8*)&Bs[wn + j * 16 + rr][kof];
#pragma unroll
      for (int i = 0; i < 4; ++i)
#pragma unroll
        for (int j = 0; j < 4; ++j)
          acc[i][j] = __builtin_amdgcn_mfma_f32_16x16x32_bf16(af[i], bfv[j], acc[i][j], 0, 0, 0);
    }
  }
  const int cr = (lane >> 4) * 4, cc2 = lane & 15;
  if constexpr (EPI == 2) {
    float kkv[4], kav[4];
#pragma unroll
    for (int j = 0; j < 4; ++j) {
      int col = n0 + wn + j * 16 + cc2;
      kkv[j] = k_k[col];
      kav[j] = k_a[col];
    }
#pragma unroll
    for (int i = 0; i < 4; ++i)
#pragma unroll
      for (int q = 0; q < 4; ++q) {
        int row = m0 + wm + i * 16 + cr + q;
        float kk4[4], p = 0.f;
#pragma unroll
        for (int j = 0; j < 4; ++j) {
          float kkc = acc[i][j][q] * kkv[j];
          kk4[j] = kkc;
          p += kkc * kkc;
        }
        p += __shfl_xor(p, 1); p += __shfl_xor(p, 2);
        p += __shfl_xor(p, 4); p += __shfl_xor(p, 8);
        float inv = 1.f / fmaxf(sqrtf(p), 1e-12f);
#pragma unroll
        for (int j = 0; j < 4; ++j) {
          int col = n0 + wn + j * 16 + cc2;
          size_t off = (size_t)row * C_ + col;
          float kkn = kk4[j] * inv;
          float a = bf2f(abf[off]);
          ahb[off] = f2bf(-kkn);
          bhb[off] = f2bf(kkn * a);
          outB[off] = f2bf(acc[i][j][q] * (1.f + (a - 1.f) * kav[j]));
        }
      }
  } else {
#pragma unroll
    for (int i = 0; i < 4; ++i)
#pragma unroll
      for (int j = 0; j < 4; ++j)
#pragma unroll
        for (int q = 0; q < 4; ++q) {
          int row = m0 + wm + i * 16 + cr + q;
          int col = n0 + wn + j * 16 + cc2;
          size_t off = (size_t)row * C_ + col;
          float v = acc[i][j][q];
          if constexpr (EPI == 0) {
            outB[off] = f2bf(v);
          } else if constexpr (EPI == 1) {
            float s = bf2f(svb[off]);
            outB[off] = f2bf(v + (vfirst[off] - v) * s);
          } else {
            outF[off] = v;
          }
        }
  }
}

// ---------------- down GEMM body (plain bf16 A staging) ----------------
template <int N, int ACT>
DI void down_body(int m0, unsigned short (*As)[64], unsigned short (*Bs)[64],
                  const unsigned short* __restrict__ A,
                  const unsigned short* __restrict__ Bt,
                  unsigned short* __restrict__ out) {
  const int tid = threadIdx.x, lane = tid & 63, wv = tid >> 6;
  const int wm = wv * 32;
  const int lr = lane >> 3, lc = (lane & 7) * 8;
  f32x4 acc[2][N / 16] = {};
  for (int kt = 0; kt < C_; kt += 64) {
    __syncthreads();
#pragma unroll
    for (int i = 0; i < 4; ++i) {
      int chunk = wv * 4 + i, r = chunk * 8 + lr;
      gl16(A + (size_t)(m0 + r) * C_ + kt + lc, (char*)&As[0][0] + chunk * 1024);
    }
#pragma unroll
    for (int i = 0; i < N / 32; ++i) {
      int chunk = wv * (N / 32) + i, r = chunk * 8 + lr;
      gl16(Bt + (size_t)r * C_ + kt + lc, (char*)&Bs[0][0] + chunk * 1024);
    }
    __syncthreads();
    const int rr = lane & 15;
#pragma unroll
    for (int kh = 0; kh < 2; ++kh) {
      const int kof = kh * 32 + (lane >> 4) * 8;
      bf16x8 af[2], bfv[N / 16];
#pragma unroll
      for (int i = 0; i < 2; ++i) af[i] = *(const bf16x8*)&As[wm + i * 16 + rr][kof];
#pragma unroll
      for (int j = 0; j < N / 16; ++j) bfv[j] = *(const bf16x8*)&Bs[j * 16 + rr][kof];
#pragma unroll
      for (int i = 0; i < 2; ++i)
#pragma unroll
        for (int j = 0; j < N / 16; ++j)
          acc[i][j] = __builtin_amdgcn_mfma_f32_16x16x32_bf16(af[i], bfv[j], acc[i][j], 0, 0, 0);
    }
  }
  const int cr = (lane >> 4) * 4, cc2 = lane & 15;
#pragma unroll
  for (int i = 0; i < 2; ++i)
#pragma unroll
    for (int j = 0; j < N / 16; ++j)
#pragma unroll
      for (int q = 0; q < 4; ++q) {
        int row = m0 + wm + i * 16 + cr + q;
        int col = j * 16 + cc2;
        float v = acc[i][j][q];
        if (ACT == 1) v = tanhf(v);
        else if (ACT == 2) v = 1.f / (1.f + expf(-v));
        out[(size_t)row * N + col] = f2bf(v);
      }
}

// merged down-GEMMs: 256 blocks (4 groups x 64 m-tiles), all prepacked mixes
__global__ __launch_bounds__(256, 2) void k_down4(
    const unsigned short* __restrict__ XMw, const unsigned short* __restrict__ XMa,
    const unsigned short* __restrict__ XMv, const unsigned short* __restrict__ XMg,
    const unsigned short* __restrict__ W1T, const unsigned short* __restrict__ A1T,
    const unsigned short* __restrict__ V1T, const unsigned short* __restrict__ G1T,
    unsigned short* __restrict__ HWB, unsigned short* __restrict__ HAB,
    unsigned short* __restrict__ HVB, unsigned short* __restrict__ HGB) {
  __shared__ __align__(16) unsigned short As[128][64];
  __shared__ __align__(16) unsigned short Bs[128][64];
  int g = blockIdx.x >> 6;
  int m0 = (blockIdx.x & 63) * 128;
  if (g == 0)      down_body<64, 1>(m0, As, Bs, XMw, W1T, HWB);
  else if (g == 1) down_body<64, 0>(m0, As, Bs, XMa, A1T, HAB);
  else if (g == 2) down_body<32, 0>(m0, As, Bs, XMv, V1T, HVB);
  else             down_body<128, 2>(m0, As, Bs, XMg, G1T, HGB);
}

// ---------------- up GEMM (K in {32,64,128}), single K pass ----------------
// MODE 0: wd = exp(-exp(-softplus(-(bias+up)) - 0.5)) -> outF (f32)
// MODE 1: sigmoid(bias+up) -> outB (bf16)
// MODE 3: up -> outB (bf16)
template <int K, int MODE>
__global__ __launch_bounds__(256, 2) void k_up(
    const unsigned short* __restrict__ A, const unsigned short* __restrict__ Bt,
    const float* __restrict__ bias, float* __restrict__ outF,
    unsigned short* __restrict__ outB) {
  __shared__ __align__(16) unsigned short As[128][K];
  __shared__ __align__(16) unsigned short Bs[128][K];
  const int tid = threadIdx.x, lane = tid & 63, wv = tid >> 6;
  const int m0 = blockIdx.y * 128, n0 = blockIdx.x * 128;
  const int wm = (wv >> 1) * 64, wn = (wv & 1) * 64;
  constexpr int LPR = K / 8;
  constexpr int RPC = 64 / LPR;
  const int lr = lane / LPR, lc = (lane % LPR) * 8;
  f32x4 acc[4][4] = {};
#pragma unroll
  for (int i = 0; i < K / 16; ++i) {
    int chunk = wv * (K / 16) + i;
    int r = chunk * RPC + lr;
    gl16(A + (size_t)(m0 + r) * K + lc, (char*)&As[0][0] + chunk * 1024);
    gl16(Bt + (size_t)(n0 + r) * K + lc, (char*)&Bs[0][0] + chunk * 1024);
  }
  __syncthreads();
  const int rr = lane & 15;
#pragma unroll
  for (int ks = 0; ks < K / 32; ++ks) {
    const int kof = ks * 32 + (lane >> 4) * 8;
    bf16x8 af[4], bfv[4];
#pragma unroll
    for (int i = 0; i < 4; ++i) af[i] = *(const bf16x8*)&As[wm + i * 16 + rr][kof];
#pragma unroll
    for (int j = 0; j < 4; ++j) bfv[j] = *(const bf16x8*)&Bs[wn + j * 16 + rr][kof];
#pragma unroll
    for (int i = 0; i < 4; ++i)
#pragma unroll
      for (int j = 0; j < 4; ++j)
        acc[i][j] = __builtin_amdgcn_mfma_f32_16x16x32_bf16(af[i], bfv[j], acc[i][j], 0, 0, 0);
  }
  const int cr = (lane >> 4) * 4, cc2 = lane & 15;
#pragma unroll
  for (int i = 0; i < 4; ++i)
#pragma unroll
    for (int j = 0; j < 4; ++j)
#pragma unroll
      for (int q = 0; q < 4; ++q) {
        int row = m0 + wm + i * 16 + cr + q;
        int col = n0 + wn + j * 16 + cc2;
        size_t off = (size_t)row * C_ + col;
        float up = acc[i][j][q];
        if (MODE == 0) {
          float z = -(bias[col] + up);
          float sp = fmaxf(z, 0.f) + log1pf(expf(-fabsf(z)));
          outF[off] = expf(-expf(-sp - 0.5f));
        } else if (MODE == 1) {
          outB[off] = f2bf(1.f / (1.f + expf(-(bias[col] + up))));
        } else {
          outB[off] = f2bf(up);
        }
      }
}

// ---------------- WKV recurrent scan: register-only, no barriers ----------------
// R8-proven structure + (64,1) launch bounds (only 1024 waves exist -> 1 wave/SIMD
// is the ceiling anyway; relaxing the VGPR cap lets the 4-slot depth-3 prefetch
// actually materialize instead of being collapsed at 72 VGPR) + pure-DPP rsum8
// (removes 2 LDS-pipe shuffles from the per-step serial chain).
__global__ __launch_bounds__(64, 1) void k_scan(
    const unsigned short* __restrict__ RB, const float* __restrict__ WD,
    const unsigned short* __restrict__ KB, const unsigned short* __restrict__ VB,
    const unsigned short* __restrict__ AHB, const unsigned short* __restrict__ BHB,
    const float* __restrict__ s0, float* __restrict__ out) {
  const int lane = threadIdx.x & 63;
  const int p = blockIdx.x;
  const int wr = p >> 7, bh = p & 127;
  const int b = bh >> 5, h = bh & 31;
  const int e = lane & 7, rl = lane >> 3;
  const int row = wr * 8 + rl;
  const int e8 = e * 8;
  const size_t base = (size_t)b * T_ * C_ + h * 64;  // elem offset at t=0
  float S[8];
  {
    const float* sp = s0 + ((size_t)(b * H_ + h) * 64 + row) * 64 + e8;
    f32x4 s0v = *(const f32x4*)sp, s1v = *(const f32x4*)(sp + 4);
#pragma unroll
    for (int j = 0; j < 4; ++j) { S[j] = s0v[j]; S[4 + j] = s1v[j]; }
  }

#define DECL_SLOT(n) bf16x8 r##n, k##n, a##n, bb##n; f32x4 wA##n, wB##n; unsigned short v##n;
  DECL_SLOT(0) DECL_SLOT(1) DECL_SLOT(2) DECL_SLOT(3)

#define ISSUE(n, t)                                              \
  {                                                              \
    int ti = (t) < T_ ? (t) : T_ - 1;                            \
    size_t eo = base + (size_t)ti * C_;                          \
    size_t ee = eo + e8;                                         \
    r##n = *(const bf16x8*)(RB + ee);                            \
    k##n = *(const bf16x8*)(KB + ee);                            \
    a##n = *(const bf16x8*)(AHB + ee);                           \
    bb##n = *(const bf16x8*)(BHB + ee);                          \
    wA##n = *(const f32x4*)(WD + ee);                            \
    wB##n = *(const f32x4*)(WD + ee + 4);                        \
    v##n = VB[eo + row];                                         \
  }

#define STEP(n, t)                                               \
  {                                                              \
    float rr[8], kk[8], aa[8], bv[8], ww[8];                     \
    _Pragma("unroll") for (int j = 0; j < 8; ++j) {              \
      rr[j] = (float)r##n[j];                                    \
      kk[j] = (float)k##n[j];                                    \
      aa[j] = (float)a##n[j];                                    \
      bv[j] = (float)bb##n[j];                                   \
    }                                                            \
    _Pragma("unroll") for (int j = 0; j < 4; ++j) {              \
      ww[j] = wA##n[j];                                          \
      ww[4 + j] = wB##n[j];                                      \
    }                                                            \
    float sa0 = S[0] * aa[0], sa1 = S[1] * aa[1];                \
    _Pragma("unroll") for (int j = 2; j < 8; j += 2) {           \
      sa0 = fmaf(S[j], aa[j], sa0);                              \
      sa1 = fmaf(S[j + 1], aa[j + 1], sa1);                      \
    }                                                            \
    float sa = rsum8(sa0 + sa1);                                 \
    float vi = bf2f(v##n);                                       \
    float o0 = 0.f, o1 = 0.f;                                    \
    _Pragma("unroll") for (int j = 0; j < 8; j += 2) {           \
      S[j] = fmaf(S[j], ww[j], fmaf(sa, bv[j], vi * kk[j]));     \
      S[j + 1] = fmaf(S[j + 1], ww[j + 1],                       \
                      fmaf(sa, bv[j + 1], vi * kk[j + 1]));      \
      o0 = fmaf(S[j], rr[j], o0);                                \
      o1 = fmaf(S[j + 1], rr[j + 1], o1);                        \
    }                                                            \
    float o = rsum8(o0 + o1);                                    \
    if (e == 0) out[base + (size_t)(t) * C_ + row] = o;          \
  }

  ISSUE(0, 0) ISSUE(1, 1) ISSUE(2, 2)
#pragma unroll 1
  for (int t = 0; t < T_; t += 4) {
    ISSUE(3, t + 3) STEP(0, t)
    ISSUE(0, t + 4) STEP(1, t + 1)
    ISSUE(1, t + 5) STEP(2, t + 2)
    ISSUE(2, t + 6) STEP(3, t + 3)
  }
#undef DECL_SLOT
#undef ISSUE
#undef STEP
}

// ---------------- GroupNorm + bonus + gate (wave per (b,t,h)) ----------------
__global__ __launch_bounds__(256) void k_gn(
    const float* __restrict__ o, const unsigned short* __restrict__ rb,
    const unsigned short* __restrict__ kb, const unsigned short* __restrict__ v,
    const unsigned short* __restrict__ g, const float* __restrict__ r_k,
    const float* __restrict__ lnw, const float* __restrict__ lnb,
    unsigned short* __restrict__ outg) {
  int wid = blockIdx.x * 4 + (threadIdx.x >> 6);
  int lane = threadIdx.x & 63;
  int h = wid & (H_ - 1);
  size_t bt = (size_t)(wid >> 5);
  size_t off = bt * C_ + h * 64 + lane;
  int c = h * 64 + lane;
  float x = o[off];
  float mu = x;
#pragma unroll
  for (int m = 1; m < 64; m <<= 1) mu += __shfl_xor(mu, m);
  mu *= (1.f / 64.f);
  float d = x - mu;
  float var = d * d;
#pragma unroll
  for (int m = 1; m < 64; m <<= 1) var += __shfl_xor(var, m);
  var *= (1.f / 64.f);
  float y = d * rsqrtf(var + 6.4e-4f) * lnw[c] + lnb[c];
  float bd = bf2f(rb[off]) * bf2f(kb[off]) * r_k[c];
#pragma unroll
  for (int m = 1; m < 64; m <<= 1) bd += __shfl_xor(bd, m);
  float res = (y + bd * bf2f(v[off])) * bf2f(g[off]);
  outg[off] = f2bf(res);
}

// ---------------- host launch ----------------
extern "C" void kernel_launch(void* const* d_in, const int* in_sizes, int n_in,
                              void* d_out, int out_size, void* d_ws, size_t ws_size,
                              hipStream_t stream) {
  const float* x      = (const float*)d_in[0];
  const float* vfirst = (const float*)d_in[1];
  const float* xprev  = (const float*)d_in[2];
  const float* wkv0   = (const float*)d_in[3];
  const float* x_r = (const float*)d_in[4];
  const float* x_w = (const float*)d_in[5];
  const float* x_k = (const float*)d_in[6];
  const float* x_v = (const float*)d_in[7];
  const float* x_a = (const float*)d_in[8];
  const float* x_g = (const float*)d_in[9];
  const float* w0 = (const float*)d_in[10];
  const float* w1 = (const float*)d_in[11];
  const float* w2 = (const float*)d_in[12];
  const float* a0 = (const float*)d_in[13];
  const float* a1 = (const float*)d_in[14];
  const float* a2 = (const float*)d_in[15];
  const float* v0 = (const float*)d_in[16];
  const float* v1 = (const float*)d_in[17];
  const float* v2 = (const float*)d_in[18];
  const float* g1 = (const float*)d_in[19];
  const float* g2 = (const float*)d_in[20];
  const float* k_k = (const float*)d_in[21];
  const float* k_a = (const float*)d_in[22];
  const float* r_k = (const float*)d_in[23];
  const float* Wr = (const float*)d_in[24];
  const float* Wk = (const float*)d_in[25];
  const float* Wv = (const float*)d_in[26];
  const float* Wo = (const float*)d_in[27];
  const float* lnw = (const float*)d_in[28];
  const float* lnb = (const float*)d_in[29];
  float* out = (float*)d_out;
  char* ws = (char*)d_ws;

  // ---- workspace layout (~239 MiB + pad) ----
  size_t woff = 0;
  auto alloc = [&](size_t n) { char* p = ws + woff; woff += n; return p; };
  char* R1 = alloc(67108864);                       // ABF|SVB -> WD (f32)
  unsigned short* ABF = (unsigned short*)R1;
  unsigned short* SVB = (unsigned short*)(R1 + 33554432);
  float* WD = (float*)R1;
  unsigned short* WT  = (unsigned short*)alloc(8388608);   // transposed big weight
  unsigned short* W1T = (unsigned short*)alloc(262144);
  unsigned short* A1T = (unsigned short*)alloc(262144);
  unsigned short* V1T = (unsigned short*)alloc(131072);
  unsigned short* G1T = (unsigned short*)alloc(524288);
  unsigned short* W2T = (unsigned short*)alloc(262144);
  unsigned short* A2T = (unsigned short*)alloc(262144);
  unsigned short* V2T = (unsigned short*)alloc(131072);
  unsigned short* G2T = (unsigned short*)alloc(524288);
  unsigned short* HWB = (unsigned short*)alloc(1048576);
  unsigned short* HAB = (unsigned short*)alloc(1048576);
  unsigned short* HVB = (unsigned short*)alloc(524288);
  unsigned short* HGB = (unsigned short*)alloc(2097152);
  unsigned short* RB  = (unsigned short*)alloc(33554432);
  unsigned short* KB  = (unsigned short*)alloc(33554432);
  unsigned short* VB  = (unsigned short*)alloc(33554432);
  unsigned short* AHB = (unsigned short*)alloc(33554432);
  unsigned short* BHB = (unsigned short*)alloc(33554432);
  alloc(65536);  // safety pad
  // Temporal overlays (regions dead at the time of each use):
  unsigned short* XMr = VB;                   // dead once V-GEMM writes VB
  unsigned short* XMv = KB;                   // dead once K-GEMM writes KB
  unsigned short* XMk = (unsigned short*)out; // d_out free until scan writes out
  unsigned short* XMw = AHB;                  // dead once K-GEMM writes AHB (down4 done)
  unsigned short* XMa = BHB;                  // dead once K-GEMM writes BHB (down4 done)
  unsigned short* XMg = RB;                   // dead once R-GEMM writes RB (down4 done)
  unsigned short* GBF  = AHB;                 // post-scan overlay (AHB dead)
  unsigned short* OUTG = BHB;                 // post-scan overlay (BHB dead)

  dim3 blk(256);
  dim3 gg(16, 64);
  dim3 g1d(1024);

  // all small weight transposes in one launch
  k_transpose8<<<dim3(1152), blk, 0, stream>>>(w1, W1T, a1, A1T, v1, V1T, g1, G1T,
                                               w2, W2T, a2, A2T, v2, V2T, g2, G2T);

  // mix prep: x read once -> all 6 mixes (XMk in d_out, XMw/XMa/XMg overlays)
  k_prep6<<<dim3(M_), blk, 0, stream>>>(x, xprev, x_r, x_v, x_k, x_w, x_a, x_g,
                                        XMr, XMv, XMk, XMw, XMa, XMg);

  // merged down-GEMMs (w,a,v,g), all prepacked bf16 mixes
  k_down4<<<dim3(256), blk, 0, stream>>>(XMw, XMa, XMv, XMg,
                                         W1T, A1T, V1T, G1T, HWB, HAB, HVB, HGB);

  // up-GEMMs needed before projections
  k_up<64, 1><<<gg, blk, 0, stream>>>(HAB, A2T, a0, nullptr, ABF);
  k_up<32, 1><<<gg, blk, 0, stream>>>(HVB, V2T, v0, nullptr, SVB);

  // R projection (XMr in VB region; writes RB, killing XMg)
  k_transpose<<<dim3(64, 64), blk, 0, stream>>>(Wr, WT, 2048, 2048);
  k_gemm_big<0><<<g1d, blk, 0, stream>>>(XMr, WT,
      nullptr, RB, nullptr, nullptr, nullptr, nullptr, nullptr, nullptr, nullptr);

  // V projection (reads XMv from KB region + SVB; writes VB, killing XMr)
  k_transpose<<<dim3(64, 64), blk, 0, stream>>>(Wv, WT, 2048, 2048);
  k_gemm_big<1><<<g1d, blk, 0, stream>>>(XMv, WT,
      nullptr, VB, SVB, vfirst, nullptr, nullptr, nullptr, nullptr, nullptr);

  // K projection (reads XMk from d_out; writes KB killing XMv, AHB killing XMw,
  // BHB killing XMa)
  k_transpose<<<dim3(64, 64), blk, 0, stream>>>(Wk, WT, 2048, 2048);
  k_gemm_big<2><<<g1d, blk, 0, stream>>>(XMk, WT,
      nullptr, KB, nullptr, nullptr, ABF, k_k, k_a, AHB, BHB);

  // w-chain up (WD overlays ABF+SVB, both consumed)
  k_up<64, 0><<<gg, blk, 0, stream>>>(HWB, W2T, w0, WD, nullptr);

  // recurrent scan -> out[b,t,c] f32 in d_out (XMk already consumed)
  k_scan<<<dim3(1024), dim3(64), 0, stream>>>(RB, WD, KB, VB, AHB, BHB, wkv0, out);

  // g-chain up (GBF overlays AHB)
  k_up<128, 3><<<gg, blk, 0, stream>>>(HGB, G2T, nullptr, nullptr, GBF);

  // GroupNorm + bonus + gate (OUTG overlays BHB)
  k_gn<<<dim3(65536), blk, 0, stream>>>(out, RB, KB, VB, GBF, r_k, lnw, lnb, OUTG);

  // final projection (overwrites d_out with the real output)
  k_transpose<<<dim3(64, 64), blk, 0, stream>>>(Wo, WT, 2048, 2048);
  k_gemm_big<3><<<g1d, blk, 0, stream>>>(OUTG, WT,
      out, nullptr, nullptr, nullptr, nullptr, nullptr, nullptr, nullptr, nullptr);
}